// Round 6
// baseline (13658.734 us; speedup 1.0000x reference)
//
#include <hip/hip_runtime.h>

#define TT 1024
#define DU 256

// workspace layout (bytes)
#define CEX_OFF   0          // bf16 c slots: [2 chain][4 grp][16 mem][16 b][16 c] (65536 B)
#define HEX_OFF   65536      // bf16 h slots: same layout (65536 B)
#define STMP_OFF  131072     // u32 stamps: [2 chain][4 grp][16 mem][16 pad] (8192 B)
#define TST_OFF   139264     // 4 groups x 4096 B test region (16384 B)
#define GCON_OFF  155648     // gok[64] u32 @ +0; gpol u32 @ +1024B (2048 B)
#define BLOB_OFF  157696     // 16 member chunks of bf16 weights
#define CHUNK_ELEMS (11*16*256)   // per-member: 11 mats x 16 cols x 256 k

typedef unsigned short ushort_t;
typedef unsigned u32;
typedef unsigned long long u64;
typedef __attribute__((ext_vector_type(8))) short short8;
typedef __attribute__((ext_vector_type(2))) unsigned long long u64x2;
typedef __attribute__((ext_vector_type(4))) float floatx4;

#define MFMA(a, b, c) __builtin_amdgcn_mfma_f32_16x16x32_bf16((a), (b), (c), 0, 0, 0)

__device__ __forceinline__ ushort_t f2bf(float f) {
  unsigned u = __float_as_uint(f);
  return (ushort_t)((u + 0x7fffu + ((u >> 16) & 1u)) >> 16);
}
__device__ __forceinline__ float sigf(float x) { return 1.0f / (1.0f + __expf(-x)); }
__device__ __forceinline__ float tanhf_(float x) {
  float t = 1.0f - 2.0f / (__expf(2.0f * fabsf(x)) + 1.0f);
  return copysignf(t, x);
}

// ---------------- slow (agent/MALL) exchange: proven baseline path ----------------
__device__ __forceinline__ short8 ldfrag(const ushort_t* p) {
  union { struct { u64 a, b; } q; short8 s; } v;
  v.q.a = __hip_atomic_load((const u64*)p,       __ATOMIC_RELAXED, __HIP_MEMORY_SCOPE_AGENT);
  v.q.b = __hip_atomic_load((const u64*)(p + 4), __ATOMIC_RELAXED, __HIP_MEMORY_SCOPE_AGENT);
  return v.s;
}
__device__ __forceinline__ void wait_slow(const u32* stG, u32 tgt, int lane) {
  const u32* p = stG + (lane & 15) * 16;
  for (;;) {
    u32 s = __hip_atomic_load(p, __ATOMIC_RELAXED, __HIP_MEMORY_SCOPE_AGENT);
    if (__all((int)(s >= tgt))) return;
    __builtin_amdgcn_s_sleep(1);
  }
}

// ---------------- fast (intra-XCD shared-L2, nt-discipline) exchange ----------------
// Producer: plain stores (write-through to shared XCD L2) -> vmcnt(0) -> stamp.
// Consumer: nt loads (no L1 allocate) -> always served by the shared L2.
// Verified end-to-end by the runtime self-test (R5: WRITE_SIZE 139MB -> 0.36MB).
__device__ __forceinline__ u32 poll_nt(const u32* p) {
  u32 s;
  asm volatile("global_load_dword %0, %1, off nt\n\ts_waitcnt vmcnt(0)"
               : "=v"(s) : "v"(p) : "memory");
  return s;
}
__device__ __forceinline__ int wait_fast(const u32* stG, u32 tgt, int lane) {
  const u32* p = stG + (lane & 15) * 16;
  int it = 0;
  for (;;) {
    u32 s = poll_nt(p);
    if (__all((int)(s >= tgt))) return 1;
    if (++it > 16384) return 0;               // bounded: never hang
    __builtin_amdgcn_s_sleep(1);
  }
}
// nt 16B fragment load — builtin so the compiler tracks deps and pipelines
__device__ __forceinline__ short8 ldfrag_nt(const ushort_t* p) {
  union { u64x2 q; short8 s; } v;
  v.q = __builtin_nontemporal_load((const u64x2*)p);
  return v.s;
}
// publish: data store -> vmcnt(0) -> stamp store
__device__ __forceinline__ void publish(ushort_t* dp, u64 v, u32* sp, u32 sv,
                                        int leader, int fast) {
  if (fast) {
    asm volatile("global_store_dwordx2 %0, %1, off" :: "v"(dp), "v"(v) : "memory");
    asm volatile("s_waitcnt vmcnt(0)" ::: "memory");
    if (leader)
      asm volatile("global_store_dword %0, %1, off" :: "v"(sp), "v"(sv) : "memory");
  } else {
    __hip_atomic_store((u64*)dp, v, __ATOMIC_RELAXED, __HIP_MEMORY_SCOPE_AGENT);
    asm volatile("s_waitcnt vmcnt(0)" ::: "memory");
    if (leader)
      __hip_atomic_store(sp, sv, __ATOMIC_RELAXED, __HIP_MEMORY_SCOPE_AGENT);
  }
}

// ---- per-group nt-pipe self-test (3 rounds, round-dependent data; all capped) ----
__device__ int test_nt(u32* tb, int mem, int lane) {
  u64* td = (u64*)tb;
  u32* tstamp = tb + 256;
  u32* tready = tb + 512;
  int ok = 1;
  for (int r = 0; r < 3; ++r) {
    u32 seq = 1u + (u32)r;
    if (lane == 0)
      __hip_atomic_store(tready + mem, seq, __ATOMIC_RELEASE, __HIP_MEMORY_SCOPE_AGENT);
    { int it = 0;
      for (;;) {
        u32 v = __hip_atomic_load(tready + (lane & 15), __ATOMIC_RELAXED,
                                  __HIP_MEMORY_SCOPE_AGENT);
        if (__all((int)(v >= seq))) break;
        if (++it > 16384) return 0;
        __builtin_amdgcn_s_sleep(2);
      } }
    if (lane < 8) {
      u64 v = 0x9E3779B97F4A7C15ull * (u64)(seq * 131u + (u32)mem * 17u + (u32)lane + 1u);
      asm volatile("global_store_dwordx2 %0, %1, off"
                   :: "v"(td + mem * 8 + lane), "v"(v) : "memory");
    }
    asm volatile("s_waitcnt vmcnt(0)" ::: "memory");
    if (lane == 0)
      asm volatile("global_store_dword %0, %1, off"
                   :: "v"(tstamp + mem * 16), "v"(seq) : "memory");
    int saw = 0;
    { int it = 0;
      for (;;) {
        u32 s = poll_nt(tstamp + (lane & 15) * 16);
        if (__all((int)(s >= seq))) { saw = 1; break; }
        if (++it > 192) break;
        __builtin_amdgcn_s_sleep(2);
      } }
    if (!saw) { ok = 0; continue; }
    u64 a = __builtin_nontemporal_load(td + lane);
    u64 b = __builtin_nontemporal_load(td + lane + 64);
    int s0 = lane >> 3, j0 = lane & 7, s1 = (lane + 64) >> 3, j1 = (lane + 64) & 7;
    u64 e0 = 0x9E3779B97F4A7C15ull * (u64)(seq * 131u + (u32)s0 * 17u + (u32)j0 + 1u);
    u64 e1 = 0x9E3779B97F4A7C15ull * (u64)(seq * 131u + (u32)s1 * 17u + (u32)j1 + 1u);
    if (!__all((int)((a == e0) && (b == e1)))) ok = 0;
  }
  return ok;
}

// ---- weight conversion: blob[mem][mat][col][k] bf16, k contiguous ----
__global__ void conv_weights(
    const float* __restrict__ wf, const float* __restrict__ wi,
    const float* __restrict__ wc, const float* __restrict__ wo,
    const float* __restrict__ rf, const float* __restrict__ ri,
    const float* __restrict__ rc, const float* __restrict__ ro,
    const float* __restrict__ pf, const float* __restrict__ pi,
    const float* __restrict__ po, ushort_t* __restrict__ blob)
{
  int id = blockIdx.x * 256 + threadIdx.x;   // 720896 total, exact
  int k   = id & 255;
  int col = (id >> 8) & 15;
  int q   = id >> 12;          // 0..175
  int m   = q % 11;
  int mm  = q / 11;
  const float* srcs[11] = {wf, wi, wc, wo, rf, ri, rc, ro, pf, pi, po};
  float v = srcs[m][k * 256 + mm * 16 + col];
  unsigned u = __float_as_uint(v);
  blob[id] = (ushort_t)((u + 0x7fffu + ((u >> 16) & 1u)) >> 16);
}

// ---- persistent recurrent kernel: 2 independent 16-row chains per group ----
// 128 blocks launched (preserves the verified chunk-of-16 XCD mapping);
// workers = bid<64 on XCDs 0-3. 4 groups x 16 members, grp=bid>>4, mem=bid&15.
// Group owns 32 batch rows = chain A (rows grp*32..+16) + chain B (+16..+32).
// Phase interleave A.P1 B.P1 A.P2 B.P2 hides every exchange round trip and the
// HBM x-prefetch drain behind the other chain's compute.
extern "C" __global__ void __launch_bounds__(128, 1)
lstm_rec(const float* __restrict__ x, const ushort_t* __restrict__ blob,
         ushort_t* __restrict__ h_ex, ushort_t* __restrict__ c_ex,
         u32* __restrict__ stamps, u32* __restrict__ tst, u32* __restrict__ gcon,
         const float* __restrict__ bfv, const float* __restrict__ biv,
         const float* __restrict__ bcv, const float* __restrict__ bov,
         float* __restrict__ out)
{
  const int bid = blockIdx.x;
  if (bid >= 64) return;                     // XCDs 4-7: retire immediately

  __shared__ ushort_t xa[2][16 * 264];       // x(t) bf16 per chain
  __shared__ float pre[2][4][16][17];
  __shared__ float pop[2][16][17];
  __shared__ float cn_f32[2][16][16];
  __shared__ ushort_t cn_bf[2][16][16];
  __shared__ ushort_t hn_bf[2][16][16];
  __shared__ float bia[4][16];
  __shared__ int s_mode;

  const int tid = threadIdx.x;
  const int wv = tid >> 6;
  const int lane = tid & 63;
  const int lr = lane & 15;
  const int lk = lane >> 4;

  const int grp = bid >> 4;                  // 0..3 (chunked dispatch: one XCD)
  const int mem = bid & 15;
  const int gb0A = grp * 32;
  const int gb0B = grp * 32 + 16;
  const int gc0 = mem * 16;

  u32* gok  = gcon;                          // [64] per-block verdicts
  u32* gpol = gcon + 256;                    // global policy word (own line)

  // ======== transport/placement self-test (wave 0 only) ========
  if (wv == 0) {
    __builtin_amdgcn_fence(__ATOMIC_ACQUIRE, "agent");   // clear L1 pre-history
    int okv = test_nt(tst + grp * 1024, mem, lane);
    if (lane == 0)
      __hip_atomic_store(gok + bid, 1u | ((u32)okv << 1),
                         __ATOMIC_RELEASE, __HIP_MEMORY_SCOPE_AGENT);
    if (bid == 0) {
      u32 pol = 0; int it = 0;
      for (;;) {
        u32 a = __hip_atomic_load(gok + lane, __ATOMIC_RELAXED, __HIP_MEMORY_SCOPE_AGENT);
        if (__all((int)(a & 1u))) { pol = __all((int)((a >> 1) & 1u)) ? 1u : 0u; break; }
        if (++it > 32768) { pol = 0; break; }
        __builtin_amdgcn_s_sleep(4);
      }
      if (lane == 0)
        __hip_atomic_store(gpol, pol + 1u, __ATOMIC_RELEASE, __HIP_MEMORY_SCOPE_AGENT);
    }
    u32 p;
    for (;;) {
      p = __hip_atomic_load(gpol, __ATOMIC_RELAXED, __HIP_MEMORY_SCOPE_AGENT);
      if (p) break;
      __builtin_amdgcn_s_sleep(4);
    }
    if (lane == 0) s_mode = (int)(p - 1u);
  }
  __syncthreads();
  const int fast = s_mode;
  int wedged = 0;
  if (fast) __builtin_amdgcn_fence(__ATOMIC_ACQUIRE, "agent");

  // ---- weight fragments -> registers (shared by both chains) ----
  const ushort_t* wb = blob + (size_t)mem * CHUNK_ELEMS;
  short8 wXa[8], wXb[8], wRa[8], wRb[8], wPa[8], wPb[8];
  {
    const int m0 = wv ? 2 : 0;
    const int p0 = wv ? 10 : 8;
    const int p1 = wv ? 10 : 9;
#pragma unroll
    for (int s = 0; s < 8; ++s) {
      const int ko = s * 32 + lk * 8;
      wXa[s] = *(const short8*)(wb + ((m0    ) * 16 + lr) * 256 + ko);
      wXb[s] = *(const short8*)(wb + ((m0 + 1) * 16 + lr) * 256 + ko);
      wRa[s] = *(const short8*)(wb + ((m0 + 4) * 16 + lr) * 256 + ko);
      wRb[s] = *(const short8*)(wb + ((m0 + 5) * 16 + lr) * 256 + ko);
      wPa[s] = *(const short8*)(wb + (p0 * 16 + lr) * 256 + ko);
      wPb[s] = *(const short8*)(wb + (p1 * 16 + lr) * 256 + ko);
    }
  }

  if (tid < 64) {
    const float* bs = (tid < 16) ? bfv : (tid < 32) ? biv : (tid < 48) ? bcv : bov;
    bia[tid >> 4][tid & 15] = bs[gc0 + (tid & 15)];
  }
  const int pb = tid >> 3, pc = (tid & 7) * 2;
  cn_f32[0][pb][pc] = 0.f; cn_f32[0][pb][pc + 1] = 0.f;
  cn_f32[1][pb][pc] = 0.f; cn_f32[1][pb][pc + 1] = 0.f;

  // exchange region pointers (per chain, per group)
  ushort_t* cXA = c_ex + (0 * 4 + grp) * 16 * 256;
  ushort_t* cXB = c_ex + (1 * 4 + grp) * 16 * 256;
  ushort_t* hXA = h_ex + (0 * 4 + grp) * 16 * 256;
  ushort_t* hXB = h_ex + (1 * 4 + grp) * 16 * 256;
  u32* stA = stamps + (0 * 4 + grp) * 256;
  u32* stB = stamps + (1 * 4 + grp) * 256;

  const int xr = tid >> 3, xc = (tid & 7) * 32;
  const int sb = lane >> 2, sc = (lane & 3) * 4;
  const floatx4 z4 = {0.f, 0.f, 0.f, 0.f};
  floatx4 aAA = z4, aAB = z4;   // chain A accumulators (this wave's 2 gates)
  floatx4 aBA = z4, aBB = z4;   // chain B
  float4 xfA[8], xfB[8];

  // ---- prologue: stage x(0) for both chains, x@W both ----
  {
    const float* xp = x + (size_t)(gb0A + xr) * TT * DU + xc;
    const float* xq = x + (size_t)(gb0B + xr) * TT * DU + xc;
#pragma unroll
    for (int u = 0; u < 8; ++u) {
      float4 f = *(const float4*)(xp + u * 4);
      *(u64*)&xa[0][xr * 264 + xc + u * 4] =
          (u64)f2bf(f.x) | ((u64)f2bf(f.y) << 16) |
          ((u64)f2bf(f.z) << 32) | ((u64)f2bf(f.w) << 48);
      float4 g = *(const float4*)(xq + u * 4);
      *(u64*)&xa[1][xr * 264 + xc + u * 4] =
          (u64)f2bf(g.x) | ((u64)f2bf(g.y) << 16) |
          ((u64)f2bf(g.z) << 32) | ((u64)f2bf(g.w) << 48);
    }
  }
  __syncthreads();
#pragma unroll
  for (int s = 0; s < 8; ++s) {
    short8 a0 = *(const short8*)&xa[0][lr * 264 + s * 32 + lk * 8];
    aAA = MFMA(a0, wXa[s], aAA); aAB = MFMA(a0, wXb[s], aAB);
    short8 a1 = *(const short8*)&xa[1][lr * 264 + s * 32 + lk * 8];
    aBA = MFMA(a1, wXa[s], aBA); aBB = MFMA(a1, wXb[s], aBB);
  }

// ---- phase macros (Q is a literal 0/1 -> all register indices static) ----
#define PH1(Q, AA, AB, hX, cX, stX)                                              \
  do {                                                                           \
    if (t > 0) {                                                                 \
      if (fast) { if (!wedged && !wait_fast(stX, 2u * (u32)t, lane)) wedged = 1; } \
      else wait_slow(stX, 2u * (u32)t, lane);                                    \
      _Pragma("unroll")                                                          \
      for (int s = 0; s < 8; ++s) {                                              \
        int k = s * 32 + lk * 8;                                                 \
        short8 hf = fast ? ldfrag_nt(hX + (k >> 4) * 256 + lr * 16 + (k & 15))   \
                         : ldfrag(hX + (k >> 4) * 256 + lr * 16 + (k & 15));     \
        AA = MFMA(hf, wRa[s], AA);                                               \
        AB = MFMA(hf, wRb[s], AB);                                               \
      }                                                                          \
    }                                                                            \
    _Pragma("unroll")                                                            \
    for (int r = 0; r < 4; ++r) {                                                \
      pre[Q][wv * 2][lk * 4 + r][lr] = AA[r];                                    \
      pre[Q][wv * 2 + 1][lk * 4 + r][lr] = AB[r];                                \
    }                                                                            \
    __syncthreads();                                                             \
    _Pragma("unroll")                                                            \
    for (int e = 0; e < 2; ++e) {                                                \
      int c = pc + e;                                                            \
      float fg = sigf(pre[Q][0][pb][c] + bia[0][c]);                             \
      float ig = sigf(pre[Q][1][pb][c] + bia[1][c]);                             \
      float ct = tanhf_(pre[Q][2][pb][c] + bia[2][c]);                           \
      float cn = fg * cn_f32[Q][pb][c] + ig * ct;                                \
      cn_f32[Q][pb][c] = cn;                                                     \
      cn_bf[Q][pb][c] = f2bf(cn);                                                \
    }                                                                            \
    __syncthreads();                                                             \
    if (wv == 0) {                                                               \
      u64 v = *(const u64*)&cn_bf[Q][sb][sc];                                    \
      publish(cX + mem * 256 + sb * 16 + sc, v, stX + mem * 16,                  \
              2u * (u32)t + 1u, lane == 0, fast);                                \
    }                                                                            \
  } while (0)

#define PH2(Q, AA, AB, cX, stX, GB0)                                             \
  do {                                                                           \
    if (fast) { if (!wedged && !wait_fast(stX, 2u * (u32)t + 1u, lane)) wedged = 1; } \
    else wait_slow(stX, 2u * (u32)t + 1u, lane);                                 \
    short8 cf[8];                                                                \
    _Pragma("unroll")                                                            \
    for (int s = 0; s < 8; ++s) {                                                \
      int k = s * 32 + lk * 8;                                                   \
      cf[s] = fast ? ldfrag_nt(cX + (k >> 4) * 256 + lr * 16 + (k & 15))         \
                   : ldfrag(cX + (k >> 4) * 256 + lr * 16 + (k & 15));           \
    }                                                                            \
    if (wv == 0) {                                                               \
      AA = z4; AB = z4;                                                          \
      _Pragma("unroll")                                                          \
      for (int s = 0; s < 8; ++s) {                                              \
        AA = MFMA(cf[s], wPa[s], AA);                                            \
        AB = MFMA(cf[s], wPb[s], AB);                                            \
      }                                                                          \
    } else {                                                                     \
      floatx4 pacc = z4;                                                         \
      _Pragma("unroll")                                                          \
      for (int s = 0; s < 8; ++s) pacc = MFMA(cf[s], wPa[s], pacc);              \
      _Pragma("unroll")                                                          \
      for (int r = 0; r < 4; ++r) pop[Q][lk * 4 + r][lr] = pacc[r];              \
    }                                                                            \
    __syncthreads();                                                             \
    _Pragma("unroll")                                                            \
    for (int e = 0; e < 2; ++e) {                                                \
      int c = pc + e;                                                            \
      float og = sigf(pre[Q][3][pb][c] + pop[Q][pb][c] + bia[3][c]);             \
      float hv = tanhf_(cn_f32[Q][pb][c]) * og;                                  \
      hn_bf[Q][pb][c] = f2bf(hv);                                                \
      if (t == TT - 1) out[((GB0) + pb) * 256 + gc0 + c] = hv;                   \
    }                                                                            \
  } while (0)

#define PH2T(Q, AA, AB, hX, stX, XF)                                             \
  do {                                                                           \
    __syncthreads();                                                             \
    if (wv == 0) {                                                               \
      u64 v = *(const u64*)&hn_bf[Q][sb][sc];                                    \
      publish(hX + mem * 256 + sb * 16 + sc, v, stX + mem * 16,                  \
              2u * (u32)t + 2u, lane == 0, fast);                                \
    }                                                                            \
    _Pragma("unroll")                                                            \
    for (int u = 0; u < 8; ++u) {                                                \
      float4 f = XF[u];                                                          \
      *(u64*)&xa[Q][xr * 264 + xc + u * 4] =                                     \
          (u64)f2bf(f.x) | ((u64)f2bf(f.y) << 16) |                              \
          ((u64)f2bf(f.z) << 32) | ((u64)f2bf(f.w) << 48);                       \
    }                                                                            \
    __syncthreads();                                                             \
    if (wv == 1) { AA = z4; AB = z4; }                                           \
    _Pragma("unroll")                                                            \
    for (int s = 0; s < 8; ++s) {                                                \
      short8 a = *(const short8*)&xa[Q][lr * 264 + s * 32 + lk * 8];             \
      AA = MFMA(a, wXa[s], AA);                                                  \
      AB = MFMA(a, wXb[s], AB);                                                  \
    }                                                                            \
  } while (0)

  for (int t = 0; t < TT; ++t) {
    PH1(0, aAA, aAB, hXA, cXA, stA);           // A: h@R, pw1, publish cA
    PH1(1, aBA, aBB, hXB, cXB, stB);           // B: fills A's c-exchange window
    if (t < TT - 1) {                          // issue both x(t+1) prefetches;
      const float* xp = x + ((size_t)(gb0A + xr) * TT + (t + 1)) * DU + xc;
      const float* xq = x + ((size_t)(gb0B + xr) * TT + (t + 1)) * DU + xc;
#pragma unroll
      for (int u = 0; u < 8; ++u) xfA[u] = *(const float4*)(xp + u * 4);
#pragma unroll
      for (int u = 0; u < 8; ++u) xfB[u] = *(const float4*)(xq + u * 4);
    }                                          // drained once in A's c-wait
    PH2(0, aAA, aAB, cXA, stA, gb0A);          // A: peephole/po, pw2 (+out)
    if (t < TT - 1) PH2T(0, aAA, aAB, hXA, stA, xfA);  // A: publish hA, x@W
    PH2(1, aBA, aBB, cXB, stB, gb0B);          // B: fills A's h-exchange window
    if (t == TT - 1) break;
    PH2T(1, aBA, aBB, hXB, stB, xfB);
  }
#undef PH1
#undef PH2
#undef PH2T
}

extern "C" void kernel_launch(void* const* d_in, const int* in_sizes, int n_in,
                              void* d_out, int out_size, void* d_ws, size_t ws_size,
                              hipStream_t stream) {
  const float* x   = (const float*)d_in[0];
  const float* bfv = (const float*)d_in[12];
  const float* biv = (const float*)d_in[13];
  const float* bcv = (const float*)d_in[14];
  const float* bov = (const float*)d_in[15];
  float* outp = (float*)d_out;

  char* ws = (char*)d_ws;
  ushort_t* c_exp = (ushort_t*)(ws + CEX_OFF);
  ushort_t* h_exp = (ushort_t*)(ws + HEX_OFF);
  u32* stmp = (u32*)(ws + STMP_OFF);
  u32* tstp = (u32*)(ws + TST_OFF);
  u32* gcon = (u32*)(ws + GCON_OFF);
  ushort_t* blob = (ushort_t*)(ws + BLOB_OFF);

  // zero exchange buffers + stamps + test/consensus regions (restart every replay)
  hipMemsetAsync(d_ws, 0, BLOB_OFF, stream);

  hipLaunchKernelGGL(conv_weights, dim3(2816), dim3(256), 0, stream,
                     (const float*)d_in[1], (const float*)d_in[2],
                     (const float*)d_in[3], (const float*)d_in[4],
                     (const float*)d_in[5], (const float*)d_in[6],
                     (const float*)d_in[7], (const float*)d_in[8],
                     (const float*)d_in[9], (const float*)d_in[10],
                     (const float*)d_in[11], blob);

  hipLaunchKernelGGL(lstm_rec, dim3(128), dim3(128), 0, stream,
                     x, (const ushort_t*)blob, h_exp, c_exp, stmp, tstp, gcon,
                     bfv, biv, bcv, bov, outp);
}

// Round 7
// 7874.949 us; speedup vs baseline: 1.7345x; 1.7345x over previous
//
#include <hip/hip_runtime.h>

#define TT 1024
#define DU 256

// workspace layout (bytes)
#define CEX_OFF   0          // bf16 c slots: [2 chain][4 grp][16 mem][16 b][16 c] (65536 B)
#define HEX_OFF   65536      // bf16 h slots: same layout (65536 B)
#define STMP_OFF  131072     // u32 stamps: [2 chain][4 grp][16 mem][16 pad] (8192 B)
#define TST_OFF   139264     // 2 test sets x 8 grp x 4096 B (65536 B)
#define GCON_OFF  204800     // gok[128] u32 @ +0; gpol u32 @ +1024 B (2048 B)
#define BLOB_OFF  206848     // 16 member chunks of bf16 weights
#define CHUNK_ELEMS (11*16*256)   // per-member: 11 mats x 16 cols x 256 k

typedef unsigned short ushort_t;
typedef unsigned u32;
typedef unsigned long long u64;
typedef __attribute__((ext_vector_type(8))) short short8;
typedef __attribute__((ext_vector_type(2))) unsigned long long u64x2;
typedef __attribute__((ext_vector_type(4))) float floatx4;

#define MFMA(a, b, c) __builtin_amdgcn_mfma_f32_16x16x32_bf16((a), (b), (c), 0, 0, 0)

__device__ __forceinline__ ushort_t f2bf(float f) {
  unsigned u = __float_as_uint(f);
  return (ushort_t)((u + 0x7fffu + ((u >> 16) & 1u)) >> 16);
}
__device__ __forceinline__ float sigf(float x) { return 1.0f / (1.0f + __expf(-x)); }
__device__ __forceinline__ float tanhf_(float x) {
  float t = 1.0f - 2.0f / (__expf(2.0f * fabsf(x)) + 1.0f);
  return copysignf(t, x);
}

// ---------------- slow (agent/MALL) exchange: proven baseline path ----------------
__device__ __forceinline__ short8 ldfrag(const ushort_t* p) {
  union { struct { u64 a, b; } q; short8 s; } v;
  v.q.a = __hip_atomic_load((const u64*)p,       __ATOMIC_RELAXED, __HIP_MEMORY_SCOPE_AGENT);
  v.q.b = __hip_atomic_load((const u64*)(p + 4), __ATOMIC_RELAXED, __HIP_MEMORY_SCOPE_AGENT);
  return v.s;
}
__device__ __forceinline__ void wait_slow(const u32* stG, u32 tgt, int lane) {
  const u32* p = stG + (lane & 15) * 16;
  for (;;) {
    u32 s = __hip_atomic_load(p, __ATOMIC_RELAXED, __HIP_MEMORY_SCOPE_AGENT);
    if (__all((int)(s >= tgt))) return;
    __builtin_amdgcn_s_sleep(1);
  }
}

// ---------------- fast (intra-XCD shared-L2, nt-discipline) exchange ----------------
// Producer: plain stores (write-through to the shared XCD L2) -> vmcnt(0) -> stamp.
// Consumer: nt loads (no L1 allocate) -> served by the shared L2.
// Proven R5: WRITE_SIZE 139 MB -> 0.36 MB, dur 6550 -> 3981 us.
__device__ __forceinline__ u32 poll_nt(const u32* p) {
  u32 s;
  asm volatile("global_load_dword %0, %1, off nt\n\ts_waitcnt vmcnt(0)"
               : "=v"(s) : "v"(p) : "memory");
  return s;
}
__device__ __forceinline__ int wait_fast(const u32* stG, u32 tgt, int lane) {
  const u32* p = stG + (lane & 15) * 16;
  int it = 0;
  for (;;) {
    u32 s = poll_nt(p);
    if (__all((int)(s >= tgt))) return 1;
    if (++it > 16384) return 0;               // bounded: never hang
    __builtin_amdgcn_s_sleep(1);
  }
}
// nt 16B fragment load — builtin so the compiler tracks deps and pipelines
__device__ __forceinline__ short8 ldfrag_nt(const ushort_t* p) {
  union { u64x2 q; short8 s; } v;
  v.q = __builtin_nontemporal_load((const u64x2*)p);
  return v.s;
}
// publish: data store -> vmcnt(0) -> stamp store
__device__ __forceinline__ void publish(ushort_t* dp, u64 v, u32* sp, u32 sv,
                                        int leader, int fast) {
  if (fast) {
    asm volatile("global_store_dwordx2 %0, %1, off" :: "v"(dp), "v"(v) : "memory");
    asm volatile("s_waitcnt vmcnt(0)" ::: "memory");
    if (leader)
      asm volatile("global_store_dword %0, %1, off" :: "v"(sp), "v"(sv) : "memory");
  } else {
    __hip_atomic_store((u64*)dp, v, __ATOMIC_RELAXED, __HIP_MEMORY_SCOPE_AGENT);
    asm volatile("s_waitcnt vmcnt(0)" ::: "memory");
    if (leader)
      __hip_atomic_store(sp, sv, __ATOMIC_RELAXED, __HIP_MEMORY_SCOPE_AGENT);
  }
}

// ---- per-group nt-pipe self-test (3 rounds, round-dependent data; all capped) ----
__device__ int test_nt(u32* tb, int mem, int lane) {
  u64* td = (u64*)tb;
  u32* tstamp = tb + 256;
  u32* tready = tb + 512;
  int ok = 1;
  for (int r = 0; r < 3; ++r) {
    u32 seq = 1u + (u32)r;
    if (lane == 0)
      __hip_atomic_store(tready + mem, seq, __ATOMIC_RELEASE, __HIP_MEMORY_SCOPE_AGENT);
    { int it = 0;
      for (;;) {
        u32 v = __hip_atomic_load(tready + (lane & 15), __ATOMIC_RELAXED,
                                  __HIP_MEMORY_SCOPE_AGENT);
        if (__all((int)(v >= seq))) break;
        if (++it > 16384) return 0;
        __builtin_amdgcn_s_sleep(2);
      } }
    if (lane < 8) {
      u64 v = 0x9E3779B97F4A7C15ull * (u64)(seq * 131u + (u32)mem * 17u + (u32)lane + 1u);
      asm volatile("global_store_dwordx2 %0, %1, off"
                   :: "v"(td + mem * 8 + lane), "v"(v) : "memory");
    }
    asm volatile("s_waitcnt vmcnt(0)" ::: "memory");
    if (lane == 0)
      asm volatile("global_store_dword %0, %1, off"
                   :: "v"(tstamp + mem * 16), "v"(seq) : "memory");
    int saw = 0;
    { int it = 0;
      for (;;) {
        u32 s = poll_nt(tstamp + (lane & 15) * 16);
        if (__all((int)(s >= seq))) { saw = 1; break; }
        if (++it > 192) break;
        __builtin_amdgcn_s_sleep(2);
      } }
    if (!saw) { ok = 0; continue; }
    u64 a = __builtin_nontemporal_load(td + lane);
    u64 b = __builtin_nontemporal_load(td + lane + 64);
    int s0 = lane >> 3, j0 = lane & 7, s1 = (lane + 64) >> 3, j1 = (lane + 64) & 7;
    u64 e0 = 0x9E3779B97F4A7C15ull * (u64)(seq * 131u + (u32)s0 * 17u + (u32)j0 + 1u);
    u64 e1 = 0x9E3779B97F4A7C15ull * (u64)(seq * 131u + (u32)s1 * 17u + (u32)j1 + 1u);
    if (!__all((int)((a == e0) && (b == e1)))) ok = 0;
  }
  return ok;
}

// ---- weight conversion: blob[mem][mat][col][k] bf16, k contiguous ----
__global__ void conv_weights(
    const float* __restrict__ wf, const float* __restrict__ wi,
    const float* __restrict__ wc, const float* __restrict__ wo,
    const float* __restrict__ rf, const float* __restrict__ ri,
    const float* __restrict__ rc, const float* __restrict__ ro,
    const float* __restrict__ pf, const float* __restrict__ pi,
    const float* __restrict__ po, ushort_t* __restrict__ blob)
{
  int id = blockIdx.x * 256 + threadIdx.x;   // 720896 total, exact
  int k   = id & 255;
  int col = (id >> 8) & 15;
  int q   = id >> 12;          // 0..175
  int m   = q % 11;
  int mm  = q / 11;
  const float* srcs[11] = {wf, wi, wc, wo, rf, ri, rc, ro, pf, pi, po};
  float v = srcs[m][k * 256 + mm * 16 + col];
  unsigned u = __float_as_uint(v);
  blob[id] = (ushort_t)((u + 0x7fffu + ((u >> 16) & 1u)) >> 16);
}

// ---- persistent recurrent kernel: 2 independent 16-row chains per group ----
// R6 lesson: dispatch is ROUND-ROBIN (XCD = bid % 8), proven by R5-pass/R6-fail
// + R6's 8x FETCH explosion. Grouping is a runtime policy:
//  1 = fast nt, RR grouping (grp=bid&7, mem=bid>>3; workers bid&7<4)  [expected]
//  2 = fast nt, CH grouping (grp=bid>>4, mem=bid&15; workers bid<64)  [fallback]
//  0 = slow agent exchange, RR grouping                               [tertiary]
// All 128 blocks self-test BOTH groupings, block 0 aggregates, then
// non-workers retire. Group g owns rows [g*32,g*32+32): chains A/B of 16 rows.
// Interleave A.P1 B.P1 A.P2 B.P2 hides exchange RTT + x-prefetch drain.
extern "C" __global__ void __launch_bounds__(128, 1)
lstm_rec(const float* __restrict__ x, const ushort_t* __restrict__ blob,
         ushort_t* __restrict__ h_ex, ushort_t* __restrict__ c_ex,
         u32* __restrict__ stamps, u32* __restrict__ tst, u32* __restrict__ gcon,
         const float* __restrict__ bfv, const float* __restrict__ biv,
         const float* __restrict__ bcv, const float* __restrict__ bov,
         float* __restrict__ out)
{
  __shared__ ushort_t xa[2][16 * 264];       // x(t) bf16 per chain
  __shared__ float pre[2][4][16][17];
  __shared__ float pop[2][16][17];
  __shared__ float cn_f32[2][16][16];
  __shared__ ushort_t cn_bf[2][16][16];
  __shared__ ushort_t hn_bf[2][16][16];
  __shared__ float bia[4][16];
  __shared__ int s_mode;

  const int tid = threadIdx.x;
  const int bid = blockIdx.x;
  const int wv = tid >> 6;
  const int lane = tid & 63;
  const int lr = lane & 15;
  const int lk = lane >> 4;

  u32* gok  = gcon;                          // [128] per-block verdicts
  u32* gpol = gcon + 256;                    // global policy word (own line)

  // ======== transport/placement self-tests on ALL blocks (wave 0 only) ========
  if (wv == 0) {
    __builtin_amdgcn_fence(__ATOMIC_ACQUIRE, "agent");   // clear L1 pre-history
    int okRR = test_nt(tst + 0 * 8192 + (bid & 7) * 1024, bid >> 3, lane);
    int okCH = test_nt(tst + 1 * 8192 + (bid >> 4) * 1024, bid & 15, lane);
    if (lane == 0)
      __hip_atomic_store(gok + bid, 1u | ((u32)okRR << 1) | ((u32)okCH << 2),
                         __ATOMIC_RELEASE, __HIP_MEMORY_SCOPE_AGENT);
    if (bid == 0) {
      u32 pol = 0; int it = 0;
      for (;;) {
        u32 a = __hip_atomic_load(gok + lane, __ATOMIC_RELAXED, __HIP_MEMORY_SCOPE_AGENT);
        u32 b = __hip_atomic_load(gok + 64 + lane, __ATOMIC_RELAXED, __HIP_MEMORY_SCOPE_AGENT);
        if (__all((int)((a & 1u) && (b & 1u)))) {
          if      (__all((int)(((a >> 1) & 1u) && ((b >> 1) & 1u)))) pol = 1;
          else if (__all((int)(((a >> 2) & 1u) && ((b >> 2) & 1u)))) pol = 2;
          break;
        }
        if (++it > 32768) { pol = 0; break; }
        __builtin_amdgcn_s_sleep(4);
      }
      if (lane == 0)
        __hip_atomic_store(gpol, pol + 1u, __ATOMIC_RELEASE, __HIP_MEMORY_SCOPE_AGENT);
    }
    u32 p;
    for (;;) {                 // block 0 always publishes (all its waits capped)
      p = __hip_atomic_load(gpol, __ATOMIC_RELAXED, __HIP_MEMORY_SCOPE_AGENT);
      if (p) break;
      __builtin_amdgcn_s_sleep(4);
    }
    if (lane == 0) s_mode = (int)(p - 1u);
  }
  __syncthreads();
  const int policy = s_mode;
  const int fast   = policy != 0;
  const int useRR  = (policy != 2);          // RR for fast-RR and slow
  const int grp = useRR ? (bid & 7) : (bid >> 4);
  const int mem = useRR ? (bid >> 3) : (bid & 15);
  const int worker = useRR ? ((bid & 7) < 4) : (bid < 64);
  if (!worker) return;                       // whole block retires (uniform)

  const int gb0A = grp * 32;
  const int gb0B = grp * 32 + 16;
  const int gc0 = mem * 16;
  int wedged = 0;
  if (fast) __builtin_amdgcn_fence(__ATOMIC_ACQUIRE, "agent");

  // ---- weight fragments -> registers (shared by both chains) ----
  const ushort_t* wb = blob + (size_t)mem * CHUNK_ELEMS;
  short8 wXa[8], wXb[8], wRa[8], wRb[8], wPa[8], wPb[8];
  {
    const int m0 = wv ? 2 : 0;
    const int p0 = wv ? 10 : 8;
    const int p1 = wv ? 10 : 9;
#pragma unroll
    for (int s = 0; s < 8; ++s) {
      const int ko = s * 32 + lk * 8;
      wXa[s] = *(const short8*)(wb + ((m0    ) * 16 + lr) * 256 + ko);
      wXb[s] = *(const short8*)(wb + ((m0 + 1) * 16 + lr) * 256 + ko);
      wRa[s] = *(const short8*)(wb + ((m0 + 4) * 16 + lr) * 256 + ko);
      wRb[s] = *(const short8*)(wb + ((m0 + 5) * 16 + lr) * 256 + ko);
      wPa[s] = *(const short8*)(wb + (p0 * 16 + lr) * 256 + ko);
      wPb[s] = *(const short8*)(wb + (p1 * 16 + lr) * 256 + ko);
    }
  }

  if (tid < 64) {
    const float* bs = (tid < 16) ? bfv : (tid < 32) ? biv : (tid < 48) ? bcv : bov;
    bia[tid >> 4][tid & 15] = bs[gc0 + (tid & 15)];
  }
  const int pb = tid >> 3, pc = (tid & 7) * 2;
  cn_f32[0][pb][pc] = 0.f; cn_f32[0][pb][pc + 1] = 0.f;
  cn_f32[1][pb][pc] = 0.f; cn_f32[1][pb][pc + 1] = 0.f;

  // exchange region pointers (per chain, per group; grp in 0..3 either policy)
  ushort_t* cXA = c_ex + (0 * 4 + grp) * 16 * 256;
  ushort_t* cXB = c_ex + (1 * 4 + grp) * 16 * 256;
  ushort_t* hXA = h_ex + (0 * 4 + grp) * 16 * 256;
  ushort_t* hXB = h_ex + (1 * 4 + grp) * 16 * 256;
  u32* stA = stamps + (0 * 4 + grp) * 256;
  u32* stB = stamps + (1 * 4 + grp) * 256;

  const int xr = tid >> 3, xc = (tid & 7) * 32;
  const int sb = lane >> 2, sc = (lane & 3) * 4;
  const floatx4 z4 = {0.f, 0.f, 0.f, 0.f};
  floatx4 aAA = z4, aAB = z4;   // chain A accumulators (this wave's 2 gates)
  floatx4 aBA = z4, aBB = z4;   // chain B
  float4 xfA[8], xfB[8];

  // ---- prologue: stage x(0) for both chains, x@W both ----
  {
    const float* xp = x + (size_t)(gb0A + xr) * TT * DU + xc;
    const float* xq = x + (size_t)(gb0B + xr) * TT * DU + xc;
#pragma unroll
    for (int u = 0; u < 8; ++u) {
      float4 f = *(const float4*)(xp + u * 4);
      *(u64*)&xa[0][xr * 264 + xc + u * 4] =
          (u64)f2bf(f.x) | ((u64)f2bf(f.y) << 16) |
          ((u64)f2bf(f.z) << 32) | ((u64)f2bf(f.w) << 48);
      float4 g = *(const float4*)(xq + u * 4);
      *(u64*)&xa[1][xr * 264 + xc + u * 4] =
          (u64)f2bf(g.x) | ((u64)f2bf(g.y) << 16) |
          ((u64)f2bf(g.z) << 32) | ((u64)f2bf(g.w) << 48);
    }
  }
  __syncthreads();
#pragma unroll
  for (int s = 0; s < 8; ++s) {
    short8 a0 = *(const short8*)&xa[0][lr * 264 + s * 32 + lk * 8];
    aAA = MFMA(a0, wXa[s], aAA); aAB = MFMA(a0, wXb[s], aAB);
    short8 a1 = *(const short8*)&xa[1][lr * 264 + s * 32 + lk * 8];
    aBA = MFMA(a1, wXa[s], aBA); aBB = MFMA(a1, wXb[s], aBB);
  }

// ---- phase macros (Q is a literal 0/1 -> all register indices static) ----
#define PH1(Q, AA, AB, hX, cX, stX)                                              \
  do {                                                                           \
    if (t > 0) {                                                                 \
      if (fast) { if (!wedged && !wait_fast(stX, 2u * (u32)t, lane)) wedged = 1; } \
      else wait_slow(stX, 2u * (u32)t, lane);                                    \
      _Pragma("unroll")                                                          \
      for (int s = 0; s < 8; ++s) {                                              \
        int k = s * 32 + lk * 8;                                                 \
        short8 hf = fast ? ldfrag_nt(hX + (k >> 4) * 256 + lr * 16 + (k & 15))   \
                         : ldfrag(hX + (k >> 4) * 256 + lr * 16 + (k & 15));     \
        AA = MFMA(hf, wRa[s], AA);                                               \
        AB = MFMA(hf, wRb[s], AB);                                               \
      }                                                                          \
    }                                                                            \
    _Pragma("unroll")                                                            \
    for (int r = 0; r < 4; ++r) {                                                \
      pre[Q][wv * 2][lk * 4 + r][lr] = AA[r];                                    \
      pre[Q][wv * 2 + 1][lk * 4 + r][lr] = AB[r];                                \
    }                                                                            \
    __syncthreads();                                                             \
    _Pragma("unroll")                                                            \
    for (int e = 0; e < 2; ++e) {                                                \
      int c = pc + e;                                                            \
      float fg = sigf(pre[Q][0][pb][c] + bia[0][c]);                             \
      float ig = sigf(pre[Q][1][pb][c] + bia[1][c]);                             \
      float ct = tanhf_(pre[Q][2][pb][c] + bia[2][c]);                           \
      float cn = fg * cn_f32[Q][pb][c] + ig * ct;                                \
      cn_f32[Q][pb][c] = cn;                                                     \
      cn_bf[Q][pb][c] = f2bf(cn);                                                \
    }                                                                            \
    __syncthreads();                                                             \
    if (wv == 0) {                                                               \
      u64 v = *(const u64*)&cn_bf[Q][sb][sc];                                    \
      publish(cX + mem * 256 + sb * 16 + sc, v, stX + mem * 16,                  \
              2u * (u32)t + 1u, lane == 0, fast);                                \
    }                                                                            \
  } while (0)

#define PH2(Q, AA, AB, cX, stX, GB0)                                             \
  do {                                                                           \
    if (fast) { if (!wedged && !wait_fast(stX, 2u * (u32)t + 1u, lane)) wedged = 1; } \
    else wait_slow(stX, 2u * (u32)t + 1u, lane);                                 \
    short8 cf[8];                                                                \
    _Pragma("unroll")                                                            \
    for (int s = 0; s < 8; ++s) {                                                \
      int k = s * 32 + lk * 8;                                                   \
      cf[s] = fast ? ldfrag_nt(cX + (k >> 4) * 256 + lr * 16 + (k & 15))         \
                   : ldfrag(cX + (k >> 4) * 256 + lr * 16 + (k & 15));           \
    }                                                                            \
    if (wv == 0) {                                                               \
      AA = z4; AB = z4;                                                          \
      _Pragma("unroll")                                                          \
      for (int s = 0; s < 8; ++s) {                                              \
        AA = MFMA(cf[s], wPa[s], AA);                                            \
        AB = MFMA(cf[s], wPb[s], AB);                                            \
      }                                                                          \
    } else {                                                                     \
      floatx4 pacc = z4;                                                         \
      _Pragma("unroll")                                                          \
      for (int s = 0; s < 8; ++s) pacc = MFMA(cf[s], wPa[s], pacc);              \
      _Pragma("unroll")                                                          \
      for (int r = 0; r < 4; ++r) pop[Q][lk * 4 + r][lr] = pacc[r];              \
    }                                                                            \
    __syncthreads();                                                             \
    _Pragma("unroll")                                                            \
    for (int e = 0; e < 2; ++e) {                                                \
      int c = pc + e;                                                            \
      float og = sigf(pre[Q][3][pb][c] + pop[Q][pb][c] + bia[3][c]);             \
      float hv = tanhf_(cn_f32[Q][pb][c]) * og;                                  \
      hn_bf[Q][pb][c] = f2bf(hv);                                                \
      if (t == TT - 1) out[((GB0) + pb) * 256 + gc0 + c] = hv;                   \
    }                                                                            \
  } while (0)

#define PH2T(Q, AA, AB, hX, stX, XF)                                             \
  do {                                                                           \
    __syncthreads();                                                             \
    if (wv == 0) {                                                               \
      u64 v = *(const u64*)&hn_bf[Q][sb][sc];                                    \
      publish(hX + mem * 256 + sb * 16 + sc, v, stX + mem * 16,                  \
              2u * (u32)t + 2u, lane == 0, fast);                                \
    }                                                                            \
    _Pragma("unroll")                                                            \
    for (int u = 0; u < 8; ++u) {                                                \
      float4 f = XF[u];                                                          \
      *(u64*)&xa[Q][xr * 264 + xc + u * 4] =                                     \
          (u64)f2bf(f.x) | ((u64)f2bf(f.y) << 16) |                              \
          ((u64)f2bf(f.z) << 32) | ((u64)f2bf(f.w) << 48);                       \
    }                                                                            \
    __syncthreads();                                                             \
    if (wv == 1) { AA = z4; AB = z4; }                                           \
    _Pragma("unroll")                                                            \
    for (int s = 0; s < 8; ++s) {                                                \
      short8 a = *(const short8*)&xa[Q][lr * 264 + s * 32 + lk * 8];             \
      AA = MFMA(a, wXa[s], AA);                                                  \
      AB = MFMA(a, wXb[s], AB);                                                  \
    }                                                                            \
  } while (0)

  for (int t = 0; t < TT; ++t) {
    PH1(0, aAA, aAB, hXA, cXA, stA);           // A: h@R, pw1, publish cA
    PH1(1, aBA, aBB, hXB, cXB, stB);           // B: fills A's c-exchange window
    if (t < TT - 1) {                          // issue both x(t+1) prefetches
      const float* xp = x + ((size_t)(gb0A + xr) * TT + (t + 1)) * DU + xc;
      const float* xq = x + ((size_t)(gb0B + xr) * TT + (t + 1)) * DU + xc;
#pragma unroll
      for (int u = 0; u < 8; ++u) xfA[u] = *(const float4*)(xp + u * 4);
#pragma unroll
      for (int u = 0; u < 8; ++u) xfB[u] = *(const float4*)(xq + u * 4);
    }
    PH2(0, aAA, aAB, cXA, stA, gb0A);          // A: peephole/po, pw2 (+out)
    if (t < TT - 1) PH2T(0, aAA, aAB, hXA, stA, xfA);  // A: publish hA, x@W
    PH2(1, aBA, aBB, cXB, stB, gb0B);          // B: fills A's h-exchange window
    if (t == TT - 1) break;
    PH2T(1, aBA, aBB, hXB, stB, xfB);
  }
#undef PH1
#undef PH2
#undef PH2T
}

extern "C" void kernel_launch(void* const* d_in, const int* in_sizes, int n_in,
                              void* d_out, int out_size, void* d_ws, size_t ws_size,
                              hipStream_t stream) {
  const float* x   = (const float*)d_in[0];
  const float* bfv = (const float*)d_in[12];
  const float* biv = (const float*)d_in[13];
  const float* bcv = (const float*)d_in[14];
  const float* bov = (const float*)d_in[15];
  float* outp = (float*)d_out;

  char* ws = (char*)d_ws;
  ushort_t* c_exp = (ushort_t*)(ws + CEX_OFF);
  ushort_t* h_exp = (ushort_t*)(ws + HEX_OFF);
  u32* stmp = (u32*)(ws + STMP_OFF);
  u32* tstp = (u32*)(ws + TST_OFF);
  u32* gcon = (u32*)(ws + GCON_OFF);
  ushort_t* blob = (ushort_t*)(ws + BLOB_OFF);

  // zero exchange buffers + stamps + test/consensus regions (restart every replay)
  hipMemsetAsync(d_ws, 0, BLOB_OFF, stream);

  hipLaunchKernelGGL(conv_weights, dim3(2816), dim3(256), 0, stream,
                     (const float*)d_in[1], (const float*)d_in[2],
                     (const float*)d_in[3], (const float*)d_in[4],
                     (const float*)d_in[5], (const float*)d_in[6],
                     (const float*)d_in[7], (const float*)d_in[8],
                     (const float*)d_in[9], (const float*)d_in[10],
                     (const float*)d_in[11], blob);

  hipLaunchKernelGGL(lstm_rec, dim3(128), dim3(128), 0, stream,
                     x, (const ushort_t*)blob, h_exp, c_exp, stmp, tstp, gcon,
                     bfv, biv, bcv, bov, outp);
}

// Round 8
// 3690.081 us; speedup vs baseline: 3.7015x; 2.1341x over previous
//
#include <hip/hip_runtime.h>

#define TT 1024
#define DU 256

// workspace layout (bytes)
#define CEX_OFF   0          // bf16 c slots: [8 grp][16 mem][16 b][16 c] (65536 B)
#define HEX_OFF   65536      // bf16 h slots: same layout (65536 B)
#define STMP_OFF  131072     // u32 stamps: [8 grp][16 mem][16 pad] (8192 B)
#define TST_OFF   139264     // 8 grp x 4096 B test region (32768 B)
#define GCON_OFF  172032     // gok[128] u32 @ +0; gpol u32 @ +1024 B (2048 B)
#define BLOB_OFF  174080     // 16 member chunks of bf16 weights
#define CHUNK_ELEMS (11*16*256)   // per-member: 11 mats x 16 cols x 256 k

typedef unsigned short ushort_t;
typedef unsigned u32;
typedef unsigned long long u64;
typedef __attribute__((ext_vector_type(8))) short short8;
typedef __attribute__((ext_vector_type(2))) unsigned long long u64x2;
typedef __attribute__((ext_vector_type(4))) float floatx4;

#define MFMA(a, b, c) __builtin_amdgcn_mfma_f32_16x16x32_bf16((a), (b), (c), 0, 0, 0)

__device__ __forceinline__ ushort_t f2bf(float f) {
  unsigned u = __float_as_uint(f);
  return (ushort_t)((u + 0x7fffu + ((u >> 16) & 1u)) >> 16);
}
__device__ __forceinline__ float sigf(float x) { return 1.0f / (1.0f + __expf(-x)); }
__device__ __forceinline__ float tanhf_(float x) {
  float t = 1.0f - 2.0f / (__expf(2.0f * fabsf(x)) + 1.0f);
  return copysignf(t, x);
}

// ---------------- slow (agent/MALL) exchange: proven baseline path ----------------
__device__ __forceinline__ short8 ldfrag(const ushort_t* p) {
  union { struct { u64 a, b; } q; short8 s; } v;
  v.q.a = __hip_atomic_load((const u64*)p,       __ATOMIC_RELAXED, __HIP_MEMORY_SCOPE_AGENT);
  v.q.b = __hip_atomic_load((const u64*)(p + 4), __ATOMIC_RELAXED, __HIP_MEMORY_SCOPE_AGENT);
  return v.s;
}
__device__ __forceinline__ void wait_slow(const u32* stG, u32 tgt, int lane) {
  const u32* p = stG + (lane & 15) * 16;
  for (;;) {
    u32 s = __hip_atomic_load(p, __ATOMIC_RELAXED, __HIP_MEMORY_SCOPE_AGENT);
    if (__all((int)(s >= tgt))) return;
    __builtin_amdgcn_s_sleep(1);
  }
}

// ---------------- fast (intra-XCD shared-L2, nt-discipline) exchange ----------------
// Producer: plain stores (write-through to the shared XCD L2) -> vmcnt(0) -> stamp.
// Consumer: nt loads (no L1 allocate) -> served by the shared L2.
// Proven R5: WRITE_SIZE 139 MB -> 0.36 MB, dur 6550 -> 3981 us, RR grouping.
// NOTE: poll_nt drains vmcnt(0) -> callers must not have long-latency loads in
// flight when polling (prefetch issue points are placed accordingly).
__device__ __forceinline__ u32 poll_nt(const u32* p) {
  u32 s;
  asm volatile("global_load_dword %0, %1, off nt\n\ts_waitcnt vmcnt(0)"
               : "=v"(s) : "v"(p) : "memory");
  return s;
}
__device__ __forceinline__ int wait_fast(const u32* stG, u32 tgt, int lane) {
  const u32* p = stG + (lane & 15) * 16;
  int it = 0;
  for (;;) {
    u32 s = poll_nt(p);
    if (__all((int)(s >= tgt))) return 1;
    if (++it > 16384) return 0;               // bounded: never hang
    __builtin_amdgcn_s_sleep(1);
  }
}
// nt 16B fragment load — builtin so the compiler tracks deps and pipelines
__device__ __forceinline__ short8 ldfrag_nt(const ushort_t* p) {
  union { u64x2 q; short8 s; } v;
  v.q = __builtin_nontemporal_load((const u64x2*)p);
  return v.s;
}

// ---- per-group nt-pipe self-test (3 rounds, round-dependent data; all capped) ----
__device__ int test_nt(u32* tb, int mem, int lane) {
  u64* td = (u64*)tb;
  u32* tstamp = tb + 256;
  u32* tready = tb + 512;
  int ok = 1;
  for (int r = 0; r < 3; ++r) {
    u32 seq = 1u + (u32)r;
    if (lane == 0)
      __hip_atomic_store(tready + mem, seq, __ATOMIC_RELEASE, __HIP_MEMORY_SCOPE_AGENT);
    { int it = 0;
      for (;;) {
        u32 v = __hip_atomic_load(tready + (lane & 15), __ATOMIC_RELAXED,
                                  __HIP_MEMORY_SCOPE_AGENT);
        if (__all((int)(v >= seq))) break;
        if (++it > 16384) return 0;
        __builtin_amdgcn_s_sleep(2);
      } }
    if (lane < 8) {
      u64 v = 0x9E3779B97F4A7C15ull * (u64)(seq * 131u + (u32)mem * 17u + (u32)lane + 1u);
      asm volatile("global_store_dwordx2 %0, %1, off"
                   :: "v"(td + mem * 8 + lane), "v"(v) : "memory");
    }
    asm volatile("s_waitcnt vmcnt(0)" ::: "memory");
    if (lane == 0)
      asm volatile("global_store_dword %0, %1, off"
                   :: "v"(tstamp + mem * 16), "v"(seq) : "memory");
    int saw = 0;
    { int it = 0;
      for (;;) {
        u32 s = poll_nt(tstamp + (lane & 15) * 16);
        if (__all((int)(s >= seq))) { saw = 1; break; }
        if (++it > 192) break;
        __builtin_amdgcn_s_sleep(2);
      } }
    if (!saw) { ok = 0; continue; }
    u64 a = __builtin_nontemporal_load(td + lane);
    u64 b = __builtin_nontemporal_load(td + lane + 64);
    int s0 = lane >> 3, j0 = lane & 7, s1 = (lane + 64) >> 3, j1 = (lane + 64) & 7;
    u64 e0 = 0x9E3779B97F4A7C15ull * (u64)(seq * 131u + (u32)s0 * 17u + (u32)j0 + 1u);
    u64 e1 = 0x9E3779B97F4A7C15ull * (u64)(seq * 131u + (u32)s1 * 17u + (u32)j1 + 1u);
    if (!__all((int)((a == e0) && (b == e1)))) ok = 0;
  }
  return ok;
}

// ---- weight conversion: blob[mem][mat][col][k] bf16, k contiguous ----
__global__ void conv_weights(
    const float* __restrict__ wf, const float* __restrict__ wi,
    const float* __restrict__ wc, const float* __restrict__ wo,
    const float* __restrict__ rf, const float* __restrict__ ri,
    const float* __restrict__ rc, const float* __restrict__ ro,
    const float* __restrict__ pf, const float* __restrict__ pi,
    const float* __restrict__ po, ushort_t* __restrict__ blob)
{
  int id = blockIdx.x * 256 + threadIdx.x;   // 720896 total, exact
  int k   = id & 255;
  int col = (id >> 8) & 15;
  int q   = id >> 12;          // 0..175
  int m   = q % 11;
  int mm  = q / 11;
  const float* srcs[11] = {wf, wi, wc, wo, rf, ri, rc, ro, pf, pi, po};
  float v = srcs[m][k * 256 + mm * 16 + col];
  unsigned u = __float_as_uint(v);
  blob[id] = (ushort_t)((u + 0x7fffu + ((u >> 16) & 1u)) >> 16);
}

// ---- persistent recurrent kernel (R5 grid: 128 blocks, 8 RR groups x 16) ----
// R7 lesson: group ticks as a convoy; only shortening the serial phase path
// helps. This version: direct-register publishes (no cn/hn LDS hops), x-staging
// fills the c-window, prefetch issue placed so stamp polls are vmcnt-clean,
// 5 barriers/step (was 8).
extern "C" __global__ void __launch_bounds__(128, 1)
lstm_rec(const float* __restrict__ x, const ushort_t* __restrict__ blob,
         ushort_t* __restrict__ h_ex, ushort_t* __restrict__ c_ex,
         u32* __restrict__ stamps, u32* __restrict__ tst, u32* __restrict__ gcon,
         const float* __restrict__ bfv, const float* __restrict__ biv,
         const float* __restrict__ bcv, const float* __restrict__ bov,
         float* __restrict__ out)
{
  __shared__ ushort_t xa[16 * 264];     // x(t) bf16, row stride 264
  __shared__ float pre[4][16][17];      // gate preacts
  __shared__ float pop[16][17];         // po partial (wave1)
  __shared__ float bia[4][16];
  __shared__ int s_mode;

  const int tid = threadIdx.x;
  const int bid = blockIdx.x;
  const int wv = tid >> 6;
  const int lane = tid & 63;
  const int lr = lane & 15;
  const int lk = lane >> 4;

  const int grp = bid & 7;                   // RR grouping (R5-proven)
  const int mem = bid >> 3;
  const int gb0 = grp * 16;
  const int gc0 = mem * 16;

  u32* gok  = gcon;                          // [128] per-block verdicts
  u32* gpol = gcon + 256;                    // global policy word (own line)

  // ======== transport self-test (wave 0 only; RR grouping only) ========
  if (wv == 0) {
    __builtin_amdgcn_fence(__ATOMIC_ACQUIRE, "agent");   // clear L1 pre-history
    int okv = test_nt(tst + grp * 1024, mem, lane);
    if (lane == 0)
      __hip_atomic_store(gok + bid, 1u | ((u32)okv << 1),
                         __ATOMIC_RELEASE, __HIP_MEMORY_SCOPE_AGENT);
    if (bid == 0) {
      u32 pol = 0; int it = 0;
      for (;;) {
        u32 a = __hip_atomic_load(gok + lane, __ATOMIC_RELAXED, __HIP_MEMORY_SCOPE_AGENT);
        u32 b = __hip_atomic_load(gok + 64 + lane, __ATOMIC_RELAXED, __HIP_MEMORY_SCOPE_AGENT);
        if (__all((int)((a & 1u) && (b & 1u)))) {
          pol = __all((int)(((a >> 1) & 1u) && ((b >> 1) & 1u))) ? 1u : 0u;
          break;
        }
        if (++it > 32768) { pol = 0; break; }
        __builtin_amdgcn_s_sleep(4);
      }
      if (lane == 0)
        __hip_atomic_store(gpol, pol + 1u, __ATOMIC_RELEASE, __HIP_MEMORY_SCOPE_AGENT);
    }
    u32 p;
    for (;;) {
      p = __hip_atomic_load(gpol, __ATOMIC_RELAXED, __HIP_MEMORY_SCOPE_AGENT);
      if (p) break;
      __builtin_amdgcn_s_sleep(4);
    }
    if (lane == 0) s_mode = (int)(p - 1u);
  }
  __syncthreads();
  const int fast = s_mode;
  int wedged = 0;
  if (fast) __builtin_amdgcn_fence(__ATOMIC_ACQUIRE, "agent");

  // ---- weight fragments -> registers ----
  const ushort_t* wb = blob + (size_t)mem * CHUNK_ELEMS;
  short8 wXa[8], wXb[8], wRa[8], wRb[8], wPa[8], wPb[8];
  {
    const int m0 = wv ? 2 : 0;
    const int p0 = wv ? 10 : 8;
    const int p1 = wv ? 10 : 9;
#pragma unroll
    for (int s = 0; s < 8; ++s) {
      const int ko = s * 32 + lk * 8;
      wXa[s] = *(const short8*)(wb + ((m0    ) * 16 + lr) * 256 + ko);
      wXb[s] = *(const short8*)(wb + ((m0 + 1) * 16 + lr) * 256 + ko);
      wRa[s] = *(const short8*)(wb + ((m0 + 4) * 16 + lr) * 256 + ko);
      wRb[s] = *(const short8*)(wb + ((m0 + 5) * 16 + lr) * 256 + ko);
      wPa[s] = *(const short8*)(wb + (p0 * 16 + lr) * 256 + ko);
      wPb[s] = *(const short8*)(wb + (p1 * 16 + lr) * 256 + ko);
    }
  }

  if (tid < 64) {
    const float* bs = (tid < 16) ? bfv : (tid < 32) ? biv : (tid < 48) ? bcv : bov;
    bia[tid >> 4][tid & 15] = bs[gc0 + (tid & 15)];
  }
  const int pb = tid >> 3, pc = (tid & 7) * 2;
  float cr0 = 0.f, cr1 = 0.f;                // own-c state, f32, in registers

  // stage x(0) -> xa (bf16)
  const int xr = tid >> 3, xc = (tid & 7) * 32;
  {
    const float* xp = x + (size_t)(gb0 + xr) * TT * DU + xc;
#pragma unroll
    for (int u = 0; u < 8; ++u) {
      float4 f = *(const float4*)(xp + u * 4);
      *(u64*)&xa[xr * 264 + xc + u * 4] =
          (u64)f2bf(f.x) | ((u64)f2bf(f.y) << 16) |
          ((u64)f2bf(f.z) << 32) | ((u64)f2bf(f.w) << 48);
    }
  }
  __syncthreads();

  const floatx4 z4 = {0.f, 0.f, 0.f, 0.f};
  floatx4 accA = z4, accB = z4;
  // prologue: x(0)@W  (c(-1)=0 so no peephole term)
#pragma unroll
  for (int s = 0; s < 8; ++s) {
    short8 a = *(const short8*)&xa[lr * 264 + s * 32 + lk * 8];
    accA = MFMA(a, wXa[s], accA);
    accB = MFMA(a, wXb[s], accB);
  }

  u32* stG = stamps + grp * 256;          // 16 members x 64B line each
  ushort_t* cG = c_ex + grp * 16 * 256;   // 16 slots x 256 ushorts (512 B)
  ushort_t* hG = h_ex + grp * 16 * 256;
  // direct-publish slots for this thread's (pb, pc..pc+1)
  u32* cSlot = (u32*)(cG + mem * 256 + pb * 16 + pc);
  u32* hSlot = (u32*)(hG + mem * 256 + pb * 16 + pc);

  for (int t = 0; t < TT; ++t) {
    // ---- h-wait (polls are vmcnt-clean: no long loads in flight) ----
    if (t > 0) {
      if (fast) { if (!wedged && !wait_fast(stG, 2u * (u32)t, lane)) wedged = 1; }
      else wait_slow(stG, 2u * (u32)t, lane);
    }
    // ---- h@R (hf loads issued BEFORE xf so hf-consume waits don't drain xf) ----
    if (t > 0) {
      short8 hf[8];
#pragma unroll
      for (int s = 0; s < 8; ++s) {
        int k = s * 32 + lk * 8;
        hf[s] = fast ? ldfrag_nt(hG + (k >> 4) * 256 + lr * 16 + (k & 15))
                     : ldfrag(hG + (k >> 4) * 256 + lr * 16 + (k & 15));
      }
      // x(t+1) prefetch: issued now, drained at c-publish vmcnt(0) (~bounded)
      float4 xf[8];
      if (t < TT - 1) {
        const float* xp = x + ((size_t)(gb0 + xr) * TT + (t + 1)) * DU + xc;
#pragma unroll
        for (int u = 0; u < 8; ++u) xf[u] = *(const float4*)(xp + u * 4);
      }
#pragma unroll
      for (int s = 0; s < 8; ++s) {
        accA = MFMA(hf[s], wRa[s], accA);
        accB = MFMA(hf[s], wRb[s], accB);
      }
#pragma unroll
      for (int r = 0; r < 4; ++r) {
        pre[wv * 2    ][lk * 4 + r][lr] = accA[r];
        pre[wv * 2 + 1][lk * 4 + r][lr] = accB[r];
      }
      __syncthreads();                                // S1: pre complete
      // ---- pointwise 1 -> cn in registers, publish c directly ----
      {
        float fg = sigf(pre[0][pb][pc] + bia[0][pc]);
        float ig = sigf(pre[1][pb][pc] + bia[1][pc]);
        float ct = tanhf_(pre[2][pb][pc] + bia[2][pc]);
        cr0 = fg * cr0 + ig * ct;
        fg = sigf(pre[0][pb][pc + 1] + bia[0][pc + 1]);
        ig = sigf(pre[1][pb][pc + 1] + bia[1][pc + 1]);
        ct = tanhf_(pre[2][pb][pc + 1] + bia[2][pc + 1]);
        cr1 = fg * cr1 + ig * ct;
      }
      u32 cw = (u32)f2bf(cr0) | ((u32)f2bf(cr1) << 16);
      if (fast)
        asm volatile("global_store_dword %0, %1, off" :: "v"(cSlot), "v"(cw) : "memory");
      else
        __hip_atomic_store(cSlot, cw, __ATOMIC_RELAXED, __HIP_MEMORY_SCOPE_AGENT);
      asm volatile("s_waitcnt vmcnt(0)" ::: "memory");  // data (+xf) drained
      __syncthreads();                                // S2: all data stores acked
      if (tid == 0) {
        u32 sv = 2u * (u32)t + 1u;
        if (fast)
          asm volatile("global_store_dword %0, %1, off" :: "v"(stG + mem * 16), "v"(sv) : "memory");
        else
          __hip_atomic_store(stG + mem * 16, sv, __ATOMIC_RELAXED, __HIP_MEMORY_SCOPE_AGENT);
      }
      // ---- stage x(t+1) into xa: fills the c-window ----
      if (t < TT - 1) {
#pragma unroll
        for (int u = 0; u < 8; ++u) {
          float4 f = xf[u];
          *(u64*)&xa[xr * 264 + xc + u * 4] =
              (u64)f2bf(f.x) | ((u64)f2bf(f.y) << 16) |
              ((u64)f2bf(f.z) << 32) | ((u64)f2bf(f.w) << 48);
        }
        __syncthreads();                              // S8: xa ready
      }
    } else {
      // t == 0: no h-part; prefetch x(1), pointwise1 with c(-1)=0
      float4 xf[8];
      {
        const float* xp = x + ((size_t)(gb0 + xr) * TT + 1) * DU + xc;
#pragma unroll
        for (int u = 0; u < 8; ++u) xf[u] = *(const float4*)(xp + u * 4);
      }
#pragma unroll
      for (int r = 0; r < 4; ++r) {
        pre[wv * 2    ][lk * 4 + r][lr] = accA[r];
        pre[wv * 2 + 1][lk * 4 + r][lr] = accB[r];
      }
      __syncthreads();                                // S1
      {
        float fg = sigf(pre[0][pb][pc] + bia[0][pc]);
        float ig = sigf(pre[1][pb][pc] + bia[1][pc]);
        float ct = tanhf_(pre[2][pb][pc] + bia[2][pc]);
        cr0 = fg * cr0 + ig * ct;
        fg = sigf(pre[0][pb][pc + 1] + bia[0][pc + 1]);
        ig = sigf(pre[1][pb][pc + 1] + bia[1][pc + 1]);
        ct = tanhf_(pre[2][pb][pc + 1] + bia[2][pc + 1]);
        cr1 = fg * cr1 + ig * ct;
      }
      u32 cw = (u32)f2bf(cr0) | ((u32)f2bf(cr1) << 16);
      if (fast)
        asm volatile("global_store_dword %0, %1, off" :: "v"(cSlot), "v"(cw) : "memory");
      else
        __hip_atomic_store(cSlot, cw, __ATOMIC_RELAXED, __HIP_MEMORY_SCOPE_AGENT);
      asm volatile("s_waitcnt vmcnt(0)" ::: "memory");
      __syncthreads();                                // S2
      if (tid == 0) {
        u32 sv = 1u;
        if (fast)
          asm volatile("global_store_dword %0, %1, off" :: "v"(stG + mem * 16), "v"(sv) : "memory");
        else
          __hip_atomic_store(stG + mem * 16, sv, __ATOMIC_RELAXED, __HIP_MEMORY_SCOPE_AGENT);
      }
#pragma unroll
      for (int u = 0; u < 8; ++u) {
        float4 f = xf[u];
        *(u64*)&xa[xr * 264 + xc + u * 4] =
            (u64)f2bf(f.x) | ((u64)f2bf(f.y) << 16) |
            ((u64)f2bf(f.z) << 32) | ((u64)f2bf(f.w) << 48);
      }
      __syncthreads();                                // S8
    }

    // ---- c-wait (clean polls: xf drained at c-publish) ----
    if (fast) { if (!wedged && !wait_fast(stG, 2u * (u32)t + 1u, lane)) wedged = 1; }
    else wait_slow(stG, 2u * (u32)t + 1u, lane);

    // ---- phase B: wave0 pf,pi (next step's acc); wave1 po -> pop ----
    {
      short8 cf[8];
#pragma unroll
      for (int s = 0; s < 8; ++s) {
        int k = s * 32 + lk * 8;
        cf[s] = fast ? ldfrag_nt(cG + (k >> 4) * 256 + lr * 16 + (k & 15))
                     : ldfrag(cG + (k >> 4) * 256 + lr * 16 + (k & 15));
      }
      if (wv == 0) {
        accA = z4; accB = z4;
#pragma unroll
        for (int s = 0; s < 8; ++s) {
          accA = MFMA(cf[s], wPa[s], accA);            // c(t)@pf
          accB = MFMA(cf[s], wPb[s], accB);            // c(t)@pi
        }
      } else {
        floatx4 pacc = z4;
#pragma unroll
        for (int s = 0; s < 8; ++s)
          pacc = MFMA(cf[s], wPa[s], pacc);            // c(t)@po
#pragma unroll
        for (int r = 0; r < 4; ++r) pop[lk * 4 + r][lr] = pacc[r];
      }
    }
    __syncthreads();                                  // S5: pop complete

    // ---- pointwise 2: o gate, h_new (registers), publish h directly ----
    float og0 = sigf(pre[3][pb][pc] + pop[pb][pc] + bia[3][pc]);
    float hv0 = tanhf_(cr0) * og0;
    float og1 = sigf(pre[3][pb][pc + 1] + pop[pb][pc + 1] + bia[3][pc + 1]);
    float hv1 = tanhf_(cr1) * og1;
    if (t == TT - 1) {
      float2 o2; o2.x = hv0; o2.y = hv1;
      *(float2*)&out[(gb0 + pb) * 256 + gc0 + pc] = o2;
      break;
    }
    u32 hw = (u32)f2bf(hv0) | ((u32)f2bf(hv1) << 16);
    if (fast)
      asm volatile("global_store_dword %0, %1, off" :: "v"(hSlot), "v"(hw) : "memory");
    else
      __hip_atomic_store(hSlot, hw, __ATOMIC_RELAXED, __HIP_MEMORY_SCOPE_AGENT);
    asm volatile("s_waitcnt vmcnt(0)" ::: "memory");
    __syncthreads();                                  // S6: all h stores acked
    if (tid == 0) {
      u32 sv = 2u * (u32)t + 2u;
      if (fast)
        asm volatile("global_store_dword %0, %1, off" :: "v"(stG + mem * 16), "v"(sv) : "memory");
      else
        __hip_atomic_store(stG + mem * 16, sv, __ATOMIC_RELAXED, __HIP_MEMORY_SCOPE_AGENT);
    }

    // ---- x@W for t+1: fills the h-window ----
    if (wv == 1) { accA = z4; accB = z4; }            // c~,o restart
#pragma unroll
    for (int s = 0; s < 8; ++s) {
      short8 a = *(const short8*)&xa[lr * 264 + s * 32 + lk * 8];
      accA = MFMA(a, wXa[s], accA);
      accB = MFMA(a, wXb[s], accB);
    }
  }
}

extern "C" void kernel_launch(void* const* d_in, const int* in_sizes, int n_in,
                              void* d_out, int out_size, void* d_ws, size_t ws_size,
                              hipStream_t stream) {
  const float* x   = (const float*)d_in[0];
  const float* bfv = (const float*)d_in[12];
  const float* biv = (const float*)d_in[13];
  const float* bcv = (const float*)d_in[14];
  const float* bov = (const float*)d_in[15];
  float* outp = (float*)d_out;

  char* ws = (char*)d_ws;
  ushort_t* c_exp = (ushort_t*)(ws + CEX_OFF);
  ushort_t* h_exp = (ushort_t*)(ws + HEX_OFF);
  u32* stmp = (u32*)(ws + STMP_OFF);
  u32* tstp = (u32*)(ws + TST_OFF);
  u32* gcon = (u32*)(ws + GCON_OFF);
  ushort_t* blob = (ushort_t*)(ws + BLOB_OFF);

  // zero exchange buffers + stamps + test/consensus regions (restart every replay)
  hipMemsetAsync(d_ws, 0, BLOB_OFF, stream);

  hipLaunchKernelGGL(conv_weights, dim3(2816), dim3(256), 0, stream,
                     (const float*)d_in[1], (const float*)d_in[2],
                     (const float*)d_in[3], (const float*)d_in[4],
                     (const float*)d_in[5], (const float*)d_in[6],
                     (const float*)d_in[7], (const float*)d_in[8],
                     (const float*)d_in[9], (const float*)d_in[10],
                     (const float*)d_in[11], blob);

  hipLaunchKernelGGL(lstm_rec, dim3(128), dim3(128), 0, stream,
                     x, (const ushort_t*)blob, h_exp, c_exp, stmp, tstp, gcon,
                     bfv, biv, bcv, bov, outp);
}

// Round 9
// 3338.115 us; speedup vs baseline: 4.0918x; 1.1054x over previous
//
#include <hip/hip_runtime.h>

#define TT 1024
#define DU 256

// workspace layout (bytes)
#define CEX_OFF   0          // bf16 c slots: [8 grp][16 mem][16 b][16 c] (65536 B)
#define HEX_OFF   65536      // bf16 h slots: same layout (65536 B)
#define STMP_OFF  131072     // u32 stamps: [8 grp][16 mem][16 pad]; word wv at +wv (8192 B)
#define TST_OFF   139264     // 8 grp x 4096 B test region (32768 B)
#define GCON_OFF  172032     // gok[128] u32 @ +0; gpol u32 @ +1024 B (2048 B)
#define BLOB_OFF  174080     // 16 member chunks of bf16 weights
#define CHUNK_ELEMS (11*16*256)   // per-member: 11 mats x 16 cols x 256 k

typedef unsigned short ushort_t;
typedef unsigned u32;
typedef unsigned long long u64;
typedef __attribute__((ext_vector_type(8))) short short8;
typedef __attribute__((ext_vector_type(2))) unsigned long long u64x2;
typedef __attribute__((ext_vector_type(4))) float floatx4;

#define MFMA(a, b, c) __builtin_amdgcn_mfma_f32_16x16x32_bf16((a), (b), (c), 0, 0, 0)

__device__ __forceinline__ ushort_t f2bf(float f) {
  unsigned u = __float_as_uint(f);
  return (ushort_t)((u + 0x7fffu + ((u >> 16) & 1u)) >> 16);
}
__device__ __forceinline__ float sigf(float x) { return 1.0f / (1.0f + __expf(-x)); }
__device__ __forceinline__ float tanhf_(float x) {
  float t = 1.0f - 2.0f / (__expf(2.0f * fabsf(x)) + 1.0f);
  return copysignf(t, x);
}

// ---------------- slow (agent/MALL) exchange: proven fallback ----------------
__device__ __forceinline__ short8 ldfrag(const ushort_t* p) {
  union { struct { u64 a, b; } q; short8 s; } v;
  v.q.a = __hip_atomic_load((const u64*)p,       __ATOMIC_RELAXED, __HIP_MEMORY_SCOPE_AGENT);
  v.q.b = __hip_atomic_load((const u64*)(p + 4), __ATOMIC_RELAXED, __HIP_MEMORY_SCOPE_AGENT);
  return v.s;
}
// per-wave stamps: word (mem*16 + wv); lanes 0..31 cover 16 mem x 2 wv
__device__ __forceinline__ void wait_slow(const u32* stG, u32 tgt, int lane) {
  const u32* p = stG + (lane & 15) * 16 + ((lane >> 4) & 1);
  for (;;) {
    u32 s = __hip_atomic_load(p, __ATOMIC_RELAXED, __HIP_MEMORY_SCOPE_AGENT);
    if (__all((int)(s >= tgt))) return;
    __builtin_amdgcn_s_sleep(1);
  }
}

// ---------------- fast (intra-XCD shared-L2, nt-discipline) exchange ----------------
// Producer: plain stores (write-through to the shared XCD L2) -> vmcnt(0) -> stamp.
// Consumer: nt loads (no L1 allocate) -> served by the shared L2.
// Proven R5/R8: WRITE_SIZE 139 MB -> 0.3 MB. RR grouping (XCD = bid % 8).
// NOTE: poll_nt drains vmcnt(0) -> no long-latency loads may be in flight at
// any poll site (xf prefetch is issued ONLY after the c-stamp, and fully
// consumed by x-staging before the next poll).
__device__ __forceinline__ u32 poll_nt(const u32* p) {
  u32 s;
  asm volatile("global_load_dword %0, %1, off nt\n\ts_waitcnt vmcnt(0)"
               : "=v"(s) : "v"(p) : "memory");
  return s;
}
__device__ __forceinline__ int wait_fast(const u32* stG, u32 tgt, int lane) {
  const u32* p = stG + (lane & 15) * 16 + ((lane >> 4) & 1);
  int it = 0;
  for (;;) {                                  // no sleep: tight ~300cy detect
    u32 s = poll_nt(p);
    if (__all((int)(s >= tgt))) return 1;
    if (++it > 16384) return 0;               // bounded: never hang
  }
}
// nt 16B fragment load — builtin so the compiler tracks deps and pipelines
__device__ __forceinline__ short8 ldfrag_nt(const ushort_t* p) {
  union { u64x2 q; short8 s; } v;
  v.q = __builtin_nontemporal_load((const u64x2*)p);
  return v.s;
}

// ---- per-group nt-pipe self-test (3 rounds, round-dependent data; all capped) ----
__device__ int test_nt(u32* tb, int mem, int lane) {
  u64* td = (u64*)tb;
  u32* tstamp = tb + 256;
  u32* tready = tb + 512;
  int ok = 1;
  for (int r = 0; r < 3; ++r) {
    u32 seq = 1u + (u32)r;
    if (lane == 0)
      __hip_atomic_store(tready + mem, seq, __ATOMIC_RELEASE, __HIP_MEMORY_SCOPE_AGENT);
    { int it = 0;
      for (;;) {
        u32 v = __hip_atomic_load(tready + (lane & 15), __ATOMIC_RELAXED,
                                  __HIP_MEMORY_SCOPE_AGENT);
        if (__all((int)(v >= seq))) break;
        if (++it > 16384) return 0;
        __builtin_amdgcn_s_sleep(2);
      } }
    if (lane < 8) {
      u64 v = 0x9E3779B97F4A7C15ull * (u64)(seq * 131u + (u32)mem * 17u + (u32)lane + 1u);
      asm volatile("global_store_dwordx2 %0, %1, off"
                   :: "v"(td + mem * 8 + lane), "v"(v) : "memory");
    }
    asm volatile("s_waitcnt vmcnt(0)" ::: "memory");
    if (lane == 0)
      asm volatile("global_store_dword %0, %1, off"
                   :: "v"(tstamp + mem * 16), "v"(seq) : "memory");
    int saw = 0;
    { int it = 0;
      for (;;) {
        u32 s = poll_nt(tstamp + (lane & 15) * 16);
        if (__all((int)(s >= seq))) { saw = 1; break; }
        if (++it > 192) break;
        __builtin_amdgcn_s_sleep(2);
      } }
    if (!saw) { ok = 0; continue; }
    u64 a = __builtin_nontemporal_load(td + lane);
    u64 b = __builtin_nontemporal_load(td + lane + 64);
    int s0 = lane >> 3, j0 = lane & 7, s1 = (lane + 64) >> 3, j1 = (lane + 64) & 7;
    u64 e0 = 0x9E3779B97F4A7C15ull * (u64)(seq * 131u + (u32)s0 * 17u + (u32)j0 + 1u);
    u64 e1 = 0x9E3779B97F4A7C15ull * (u64)(seq * 131u + (u32)s1 * 17u + (u32)j1 + 1u);
    if (!__all((int)((a == e0) && (b == e1)))) ok = 0;
  }
  return ok;
}

// ---- weight conversion: blob[mem][mat][col][k] bf16, k contiguous ----
__global__ void conv_weights(
    const float* __restrict__ wf, const float* __restrict__ wi,
    const float* __restrict__ wc, const float* __restrict__ wo,
    const float* __restrict__ rf, const float* __restrict__ ri,
    const float* __restrict__ rc, const float* __restrict__ ro,
    const float* __restrict__ pf, const float* __restrict__ pi,
    const float* __restrict__ po, ushort_t* __restrict__ blob)
{
  int id = blockIdx.x * 256 + threadIdx.x;   // 720896 total, exact
  int k   = id & 255;
  int col = (id >> 8) & 15;
  int q   = id >> 12;          // 0..175
  int m   = q % 11;
  int mm  = q / 11;
  const float* srcs[11] = {wf, wi, wc, wo, rf, ri, rc, ro, pf, pi, po};
  float v = srcs[m][k * 256 + mm * 16 + col];
  unsigned u = __float_as_uint(v);
  blob[id] = (ushort_t)((u + 0x7fffu + ((u >> 16) & 1u)) >> 16);
}

// ---- persistent recurrent kernel (128 blocks, 8 RR groups x 16 members) ----
// R8 lessons applied: (1) xf prefetch issued AFTER the c-stamp so the publish
// vmcnt(0) drains only the c-store ack (R8 serialized ~900cy of HBM latency
// into every exchange); (2) per-wave stamps [mem][wv] remove the
// barrier-before-stamp from both publish paths; (3) 3 barriers/step.
extern "C" __global__ void __launch_bounds__(128, 1)
lstm_rec(const float* __restrict__ x, const ushort_t* __restrict__ blob,
         ushort_t* __restrict__ h_ex, ushort_t* __restrict__ c_ex,
         u32* __restrict__ stamps, u32* __restrict__ tst, u32* __restrict__ gcon,
         const float* __restrict__ bfv, const float* __restrict__ biv,
         const float* __restrict__ bcv, const float* __restrict__ bov,
         float* __restrict__ out)
{
  __shared__ ushort_t xa[16 * 264];     // x(t) bf16, row stride 264
  __shared__ float pre[4][16][17];      // gate preacts
  __shared__ float pop[16][17];         // po partial (wave1)
  __shared__ float bia[4][16];
  __shared__ int s_mode;

  const int tid = threadIdx.x;
  const int bid = blockIdx.x;
  const int wv = tid >> 6;
  const int lane = tid & 63;
  const int lr = lane & 15;
  const int lk = lane >> 4;

  const int grp = bid & 7;                   // RR grouping (R5/R8-proven)
  const int mem = bid >> 3;
  const int gb0 = grp * 16;
  const int gc0 = mem * 16;

  u32* gok  = gcon;                          // [128] per-block verdicts
  u32* gpol = gcon + 256;                    // global policy word (own line)

  // ======== transport self-test (wave 0 only) ========
  if (wv == 0) {
    __builtin_amdgcn_fence(__ATOMIC_ACQUIRE, "agent");   // clear L1 pre-history
    int okv = test_nt(tst + grp * 1024, mem, lane);
    if (lane == 0)
      __hip_atomic_store(gok + bid, 1u | ((u32)okv << 1),
                         __ATOMIC_RELEASE, __HIP_MEMORY_SCOPE_AGENT);
    if (bid == 0) {
      u32 pol = 0; int it = 0;
      for (;;) {
        u32 a = __hip_atomic_load(gok + lane, __ATOMIC_RELAXED, __HIP_MEMORY_SCOPE_AGENT);
        u32 b = __hip_atomic_load(gok + 64 + lane, __ATOMIC_RELAXED, __HIP_MEMORY_SCOPE_AGENT);
        if (__all((int)((a & 1u) && (b & 1u)))) {
          pol = __all((int)(((a >> 1) & 1u) && ((b >> 1) & 1u))) ? 1u : 0u;
          break;
        }
        if (++it > 32768) { pol = 0; break; }
        __builtin_amdgcn_s_sleep(4);
      }
      if (lane == 0)
        __hip_atomic_store(gpol, pol + 1u, __ATOMIC_RELEASE, __HIP_MEMORY_SCOPE_AGENT);
    }
    u32 p;
    for (;;) {
      p = __hip_atomic_load(gpol, __ATOMIC_RELAXED, __HIP_MEMORY_SCOPE_AGENT);
      if (p) break;
      __builtin_amdgcn_s_sleep(4);
    }
    if (lane == 0) s_mode = (int)(p - 1u);
  }
  __syncthreads();
  const int fast = s_mode;
  int wedged = 0;
  if (fast) __builtin_amdgcn_fence(__ATOMIC_ACQUIRE, "agent");

  // ---- weight fragments -> registers ----
  const ushort_t* wb = blob + (size_t)mem * CHUNK_ELEMS;
  short8 wXa[8], wXb[8], wRa[8], wRb[8], wPa[8], wPb[8];
  {
    const int m0 = wv ? 2 : 0;
    const int p0 = wv ? 10 : 8;
    const int p1 = wv ? 10 : 9;
#pragma unroll
    for (int s = 0; s < 8; ++s) {
      const int ko = s * 32 + lk * 8;
      wXa[s] = *(const short8*)(wb + ((m0    ) * 16 + lr) * 256 + ko);
      wXb[s] = *(const short8*)(wb + ((m0 + 1) * 16 + lr) * 256 + ko);
      wRa[s] = *(const short8*)(wb + ((m0 + 4) * 16 + lr) * 256 + ko);
      wRb[s] = *(const short8*)(wb + ((m0 + 5) * 16 + lr) * 256 + ko);
      wPa[s] = *(const short8*)(wb + (p0 * 16 + lr) * 256 + ko);
      wPb[s] = *(const short8*)(wb + (p1 * 16 + lr) * 256 + ko);
    }
  }

  if (tid < 64) {
    const float* bs = (tid < 16) ? bfv : (tid < 32) ? biv : (tid < 48) ? bcv : bov;
    bia[tid >> 4][tid & 15] = bs[gc0 + (tid & 15)];
  }
  const int pb = tid >> 3, pc = (tid & 7) * 2;   // wave0: b 0-7; wave1: b 8-15
  float cr0 = 0.f, cr1 = 0.f;                    // own-c state, f32, registers

  // stage x(0) -> xa (bf16)
  const int xr = tid >> 3, xc = (tid & 7) * 32;
  {
    const float* xp = x + (size_t)(gb0 + xr) * TT * DU + xc;
#pragma unroll
    for (int u = 0; u < 8; ++u) {
      float4 f = *(const float4*)(xp + u * 4);
      *(u64*)&xa[xr * 264 + xc + u * 4] =
          (u64)f2bf(f.x) | ((u64)f2bf(f.y) << 16) |
          ((u64)f2bf(f.z) << 32) | ((u64)f2bf(f.w) << 48);
    }
  }
  __syncthreads();

  const floatx4 z4 = {0.f, 0.f, 0.f, 0.f};
  floatx4 accA = z4, accB = z4;
  // prologue: x(0)@W  (c(-1)=0 so no peephole term)
#pragma unroll
  for (int s = 0; s < 8; ++s) {
    short8 a = *(const short8*)&xa[lr * 264 + s * 32 + lk * 8];
    accA = MFMA(a, wXa[s], accA);
    accB = MFMA(a, wXb[s], accB);
  }

  u32* stG = stamps + grp * 256;          // member line 64B; word wv at +wv
  ushort_t* cG = c_ex + grp * 16 * 256;   // 16 slots x 256 ushorts
  ushort_t* hG = h_ex + grp * 16 * 256;
  u32* cSlot = (u32*)(cG + mem * 256 + pb * 16 + pc);
  u32* hSlot = (u32*)(hG + mem * 256 + pb * 16 + pc);
  u32* mySt  = stG + mem * 16 + wv;       // this wave's stamp word

  for (int t = 0; t < TT; ++t) {
    // ---- h-wait + h@R (polls clean: nothing in flight) ----
    if (t > 0) {
      if (fast) { if (!wedged && !wait_fast(stG, 2u * (u32)t, lane)) wedged = 1; }
      else wait_slow(stG, 2u * (u32)t, lane);
      short8 hf[8];
#pragma unroll
      for (int s = 0; s < 8; ++s) {
        int k = s * 32 + lk * 8;
        hf[s] = fast ? ldfrag_nt(hG + (k >> 4) * 256 + lr * 16 + (k & 15))
                     : ldfrag(hG + (k >> 4) * 256 + lr * 16 + (k & 15));
      }
#pragma unroll
      for (int s = 0; s < 8; ++s) {
        accA = MFMA(hf[s], wRa[s], accA);
        accB = MFMA(hf[s], wRb[s], accB);
      }
    }
#pragma unroll
    for (int r = 0; r < 4; ++r) {
      pre[wv * 2    ][lk * 4 + r][lr] = accA[r];
      pre[wv * 2 + 1][lk * 4 + r][lr] = accB[r];
    }
    __syncthreads();                                  // S1: pre complete

    // ---- pointwise 1 (registers) -> publish c (per-wave, no barrier) ----
    {
      float fg = sigf(pre[0][pb][pc] + bia[0][pc]);
      float ig = sigf(pre[1][pb][pc] + bia[1][pc]);
      float ct = tanhf_(pre[2][pb][pc] + bia[2][pc]);
      cr0 = fg * cr0 + ig * ct;
      fg = sigf(pre[0][pb][pc + 1] + bia[0][pc + 1]);
      ig = sigf(pre[1][pb][pc + 1] + bia[1][pc + 1]);
      ct = tanhf_(pre[2][pb][pc + 1] + bia[2][pc + 1]);
      cr1 = fg * cr1 + ig * ct;
    }
    {
      u32 cw = (u32)f2bf(cr0) | ((u32)f2bf(cr1) << 16);
      if (fast)
        asm volatile("global_store_dword %0, %1, off" :: "v"(cSlot), "v"(cw) : "memory");
      else
        __hip_atomic_store(cSlot, cw, __ATOMIC_RELAXED, __HIP_MEMORY_SCOPE_AGENT);
      asm volatile("s_waitcnt vmcnt(0)" ::: "memory");  // c-store ack ONLY (~250cy)
      if (lane == 0) {
        u32 sv = 2u * (u32)t + 1u;
        if (fast)
          asm volatile("global_store_dword %0, %1, off" :: "v"(mySt), "v"(sv) : "memory");
        else
          __hip_atomic_store(mySt, sv, __ATOMIC_RELAXED, __HIP_MEMORY_SCOPE_AGENT);
      }
    }

    // ---- x(t+1): issue AFTER the stamp; stage fills the c-window ----
    if (t < TT - 1) {
      float4 xf[8];
      const float* xp = x + ((size_t)(gb0 + xr) * TT + (t + 1)) * DU + xc;
#pragma unroll
      for (int u = 0; u < 8; ++u) xf[u] = *(const float4*)(xp + u * 4);
#pragma unroll
      for (int u = 0; u < 8; ++u) {
        float4 f = xf[u];
        *(u64*)&xa[xr * 264 + xc + u * 4] =
            (u64)f2bf(f.x) | ((u64)f2bf(f.y) << 16) |
            ((u64)f2bf(f.z) << 32) | ((u64)f2bf(f.w) << 48);
      }
      __syncthreads();                                // S8: xa ready (in c-window)
    }

    // ---- c-wait (clean polls: xf fully consumed by staging) ----
    if (fast) { if (!wedged && !wait_fast(stG, 2u * (u32)t + 1u, lane)) wedged = 1; }
    else wait_slow(stG, 2u * (u32)t + 1u, lane);

    // ---- phase B: wave0 pf,pi (next step's acc); wave1 po -> pop ----
    {
      short8 cf[8];
#pragma unroll
      for (int s = 0; s < 8; ++s) {
        int k = s * 32 + lk * 8;
        cf[s] = fast ? ldfrag_nt(cG + (k >> 4) * 256 + lr * 16 + (k & 15))
                     : ldfrag(cG + (k >> 4) * 256 + lr * 16 + (k & 15));
      }
      if (wv == 0) {
        accA = z4; accB = z4;
#pragma unroll
        for (int s = 0; s < 8; ++s) {
          accA = MFMA(cf[s], wPa[s], accA);            // c(t)@pf
          accB = MFMA(cf[s], wPb[s], accB);            // c(t)@pi
        }
      } else {
        floatx4 pacc = z4;
#pragma unroll
        for (int s = 0; s < 8; ++s)
          pacc = MFMA(cf[s], wPa[s], pacc);            // c(t)@po
#pragma unroll
        for (int r = 0; r < 4; ++r) pop[lk * 4 + r][lr] = pacc[r];
      }
    }
    __syncthreads();                                  // S5: pop complete

    // ---- pointwise 2 -> publish h (per-wave, no barrier) ----
    float og0 = sigf(pre[3][pb][pc] + pop[pb][pc] + bia[3][pc]);
    float hv0 = tanhf_(cr0) * og0;
    float og1 = sigf(pre[3][pb][pc + 1] + pop[pb][pc + 1] + bia[3][pc + 1]);
    float hv1 = tanhf_(cr1) * og1;
    if (t == TT - 1) {
      float2 o2; o2.x = hv0; o2.y = hv1;
      *(float2*)&out[(gb0 + pb) * 256 + gc0 + pc] = o2;
      break;
    }
    {
      u32 hw = (u32)f2bf(hv0) | ((u32)f2bf(hv1) << 16);
      if (fast)
        asm volatile("global_store_dword %0, %1, off" :: "v"(hSlot), "v"(hw) : "memory");
      else
        __hip_atomic_store(hSlot, hw, __ATOMIC_RELAXED, __HIP_MEMORY_SCOPE_AGENT);
      asm volatile("s_waitcnt vmcnt(0)" ::: "memory");  // h-store ack ONLY
      if (lane == 0) {
        u32 sv = 2u * (u32)t + 2u;
        if (fast)
          asm volatile("global_store_dword %0, %1, off" :: "v"(mySt), "v"(sv) : "memory");
        else
          __hip_atomic_store(mySt, sv, __ATOMIC_RELAXED, __HIP_MEMORY_SCOPE_AGENT);
      }
    }

    // ---- x@W for t+1: fills the h-window (LDS only, polls stay clean) ----
    if (wv == 1) { accA = z4; accB = z4; }            // c~,o restart
#pragma unroll
    for (int s = 0; s < 8; ++s) {
      short8 a = *(const short8*)&xa[lr * 264 + s * 32 + lk * 8];
      accA = MFMA(a, wXa[s], accA);
      accB = MFMA(a, wXb[s], accB);
    }
  }
}

extern "C" void kernel_launch(void* const* d_in, const int* in_sizes, int n_in,
                              void* d_out, int out_size, void* d_ws, size_t ws_size,
                              hipStream_t stream) {
  const float* x   = (const float*)d_in[0];
  const float* bfv = (const float*)d_in[12];
  const float* biv = (const float*)d_in[13];
  const float* bcv = (const float*)d_in[14];
  const float* bov = (const float*)d_in[15];
  float* outp = (float*)d_out;

  char* ws = (char*)d_ws;
  ushort_t* c_exp = (ushort_t*)(ws + CEX_OFF);
  ushort_t* h_exp = (ushort_t*)(ws + HEX_OFF);
  u32* stmp = (u32*)(ws + STMP_OFF);
  u32* tstp = (u32*)(ws + TST_OFF);
  u32* gcon = (u32*)(ws + GCON_OFF);
  ushort_t* blob = (ushort_t*)(ws + BLOB_OFF);

  // zero exchange buffers + stamps + test/consensus regions (restart every replay)
  hipMemsetAsync(d_ws, 0, BLOB_OFF, stream);

  hipLaunchKernelGGL(conv_weights, dim3(2816), dim3(256), 0, stream,
                     (const float*)d_in[1], (const float*)d_in[2],
                     (const float*)d_in[3], (const float*)d_in[4],
                     (const float*)d_in[5], (const float*)d_in[6],
                     (const float*)d_in[7], (const float*)d_in[8],
                     (const float*)d_in[9], (const float*)d_in[10],
                     (const float*)d_in[11], blob);

  hipLaunchKernelGGL(lstm_rec, dim3(128), dim3(128), 0, stream,
                     x, (const ushort_t*)blob, h_exp, c_exp, stmp, tstp, gcon,
                     bfv, biv, bcv, bov, outp);
}